// Round 3
// baseline (938.583 us; speedup 1.0000x reference)
//
#include <hip/hip_runtime.h>

#define HEADS 4
#define CPH 32
#define FDIM 128
#define NEG_SLOPE 0.2f
#define EPS_DEN 1e-16f

// ---------------------------------------------------------------------------
// CSR construction (unchanged this round; fill's 109MB write-amp is next target)
// ---------------------------------------------------------------------------

__global__ void count_kernel(const int* __restrict__ dst, int* __restrict__ deg, int E) {
    int i = blockIdx.x * blockDim.x + threadIdx.x;
    int stride = gridDim.x * blockDim.x;
    for (; i < E; i += stride) atomicAdd(&deg[dst[i]], 1);
}

__global__ void scan_sum_kernel(const int* __restrict__ deg, int* __restrict__ part, int n) {
    __shared__ int sd[256];
    int t = threadIdx.x;
    int base = blockIdx.x * 1024 + t * 4;
    int s = 0;
#pragma unroll
    for (int j = 0; j < 4; ++j) { int i = base + j; if (i < n) s += deg[i] + 1; }
    sd[t] = s;
    __syncthreads();
    for (int d = 128; d; d >>= 1) { if (t < d) sd[t] += sd[t + d]; __syncthreads(); }
    if (t == 0) part[blockIdx.x] = sd[0];
}

__global__ void scan_part_kernel(int* part, int nblk, int* row_ptr, int n) {
    if (blockIdx.x == 0 && threadIdx.x == 0) {
        int run = 0;
        for (int i = 0; i < nblk; ++i) { int v = part[i]; part[i] = run; run += v; }
        row_ptr[n] = run;
    }
}

__global__ void scan_final_kernel(const int* __restrict__ deg, const int* __restrict__ part,
                                  int* __restrict__ row_ptr, int* __restrict__ cursor, int n) {
    __shared__ int sd[256];
    int t = threadIdx.x;
    int base = blockIdx.x * 1024 + t * 4;
    int v[4]; int s = 0;
#pragma unroll
    for (int j = 0; j < 4; ++j) { int i = base + j; v[j] = (i < n) ? deg[i] + 1 : 0; s += v[j]; }
    sd[t] = s;
    __syncthreads();
    for (int d = 1; d < 256; d <<= 1) {
        int x = sd[t];
        int y = (t >= d) ? sd[t - d] : 0;
        __syncthreads();
        sd[t] = x + y;
        __syncthreads();
    }
    int off = part[blockIdx.x] + sd[t] - s;
#pragma unroll
    for (int j = 0; j < 4; ++j) {
        int i = base + j;
        if (i < n) { row_ptr[i] = off; cursor[i] = off; off += v[j]; }
    }
}

__global__ void fill_kernel(const int* __restrict__ ei, int* __restrict__ cursor,
                            int* __restrict__ csr_src, int E, int N) {
    int ET = E + N;
    int i = blockIdx.x * blockDim.x + threadIdx.x;
    int stride = gridDim.x * blockDim.x;
    for (; i < ET; i += stride) {
        int s, d;
        if (i < E) { s = ei[i]; d = ei[E + i]; }
        else       { s = i - E; d = s; }
        int p = atomicAdd(&cursor[d], 1);
        csr_src[p] = s;
    }
}

// ---------------------------------------------------------------------------
// Fused GEMM (h = X @ W) + alpha_src/alpha_dst per node
// Tile: 128 rows x 128 cols, K-chunks of 32. Thread = 8x8 -> 64 fma / 4 ds_read_b128.
// ---------------------------------------------------------------------------
#define GM_LD 132

__global__ __launch_bounds__(256) void gemm_alpha_kernel(
        const float* __restrict__ X, const float* __restrict__ W,
        const float* __restrict__ a_src, const float* __restrict__ a_dst,
        float* __restrict__ H, float* __restrict__ ASo, float* __restrict__ ADo, int n) {
    __shared__ float As[32][GM_LD];  // transposed A chunk: As[k][row], 128 rows
    __shared__ float Bs[32][128];
    int tid = threadIdx.x;
    int block_row = blockIdx.x * 128;
    int tc = tid & 15;     // col group: cols tc*8 .. tc*8+7 (one head each)
    int tr = tid >> 4;     // row group: rows tr*8 ..
    int r0 = tr * 8;
    int c0 = tc * 8;
    float acc[8][8];
#pragma unroll
    for (int i = 0; i < 8; ++i)
#pragma unroll
        for (int j = 0; j < 8; ++j) acc[i][j] = 0.f;

    for (int k0 = 0; k0 < 128; k0 += 32) {
        // stage A (128x32) transposed: 1024 float4, 4 per thread
#pragma unroll
        for (int t = tid; t < 1024; t += 256) {
            int row = t >> 3;
            int kk = (t & 7) << 2;
            int grow = block_row + row;
            float4 v = make_float4(0.f, 0.f, 0.f, 0.f);
            if (grow < n) v = *(const float4*)&X[(size_t)grow * FDIM + k0 + kk];
            As[kk + 0][row] = v.x; As[kk + 1][row] = v.y;
            As[kk + 2][row] = v.z; As[kk + 3][row] = v.w;
        }
        // stage B (32x128): 1024 float4, 4 per thread
#pragma unroll
        for (int t = tid; t < 1024; t += 256) {
            int kr = t >> 5;
            int c4 = (t & 31) << 2;
            *(float4*)&Bs[kr][c4] = *(const float4*)&W[(size_t)(k0 + kr) * FDIM + c4];
        }
        __syncthreads();
#pragma unroll
        for (int k = 0; k < 32; ++k) {
            float4 a0 = *(const float4*)&As[k][r0];
            float4 a1 = *(const float4*)&As[k][r0 + 4];
            float4 b0 = *(const float4*)&Bs[k][c0];
            float4 b1 = *(const float4*)&Bs[k][c0 + 4];
            float av[8] = {a0.x, a0.y, a0.z, a0.w, a1.x, a1.y, a1.z, a1.w};
            float bv[8] = {b0.x, b0.y, b0.z, b0.w, b1.x, b1.y, b1.z, b1.w};
#pragma unroll
            for (int i = 0; i < 8; ++i)
#pragma unroll
                for (int j = 0; j < 8; ++j) acc[i][j] = fmaf(av[i], bv[j], acc[i][j]);
        }
        __syncthreads();
    }

    // epilogue: store H + fused alpha dots. This thread's 8 cols lie in ONE head.
    int head = tc >> 2;            // c0>>5
    int co = (tc & 3) * 8;         // offset within head's 32 channels
    float ws[8], wd[8];
#pragma unroll
    for (int j = 0; j < 8; ++j) {
        ws[j] = a_src[head * CPH + co + j];
        wd[j] = a_dst[head * CPH + co + j];
    }
#pragma unroll
    for (int i = 0; i < 8; ++i) {
        int grow = block_row + r0 + i;
        bool ok = grow < n;
        if (ok) {
            *(float4*)&H[(size_t)grow * FDIM + c0] =
                make_float4(acc[i][0], acc[i][1], acc[i][2], acc[i][3]);
            *(float4*)&H[(size_t)grow * FDIM + c0 + 4] =
                make_float4(acc[i][4], acc[i][5], acc[i][6], acc[i][7]);
        }
        float ps = 0.f, pd = 0.f;
#pragma unroll
        for (int j = 0; j < 8; ++j) {
            ps = fmaf(acc[i][j], ws[j], ps);
            pd = fmaf(acc[i][j], wd[j], pd);
        }
        // reduce over the 4 threads (consecutive lanes) sharing this row+head
        ps += __shfl_xor(ps, 1); ps += __shfl_xor(ps, 2);
        pd += __shfl_xor(pd, 1); pd += __shfl_xor(pd, 2);
        if (ok && (tc & 3) == 0) {
            ASo[(size_t)grow * HEADS + head] = ps;
            ADo[(size_t)grow * HEADS + head] = pd;
        }
    }
}

// ---------------------------------------------------------------------------
// Aggregation: one wave per dst node. Online segment-softmax + weighted sum.
// Lanes 0-31: even edges, 32-63: odd edges; lane owns 4 channels c0=4*(lane&31).
// 6-deep float4 gather pipeline (addresses all known at chunk start).
// ---------------------------------------------------------------------------
__global__ __launch_bounds__(256) void aggregate_kernel(
        const float* __restrict__ H, const float* __restrict__ ASi, const float* __restrict__ ADi,
        const int* __restrict__ row_ptr, const int* __restrict__ csr_src,
        const float* __restrict__ bias, float* __restrict__ OUT, int n, int relu) {
    int wid = (int)((blockIdx.x * (size_t)blockDim.x + threadIdx.x) >> 6);
    if (wid >= n) return;
    int lane = threadIdx.x & 63;
    int half = lane >> 5;       // 0: even edges, 1: odd edges
    int lq   = lane & 31;
    int head = lq >> 3;
    int c0   = lq << 2;
    const float* Hc = H + c0;

    int start = row_ptr[wid];
    int end   = row_ptr[wid + 1];
    float4 adv = *(const float4*)&ADi[(size_t)wid * HEADS];

    float m = -INFINITY;
    float dn = 0.f;
    float a0 = 0.f, a1 = 0.f, a2 = 0.f, a3 = 0.f;

    for (int base = start; base < end; base += 64) {
        int cnt = min(64, end - base);
        int idx = base + lane;
        float e0 = -INFINITY, e1 = -INFINITY, e2 = -INFINITY, e3 = -INFINITY;
        int my_src = 0;
        if (idx < end) {
            my_src = csr_src[idx];
            float4 as = *(const float4*)&ASi[(size_t)my_src * HEADS];
            float t;
            t = as.x + adv.x; e0 = t > 0.f ? t : NEG_SLOPE * t;
            t = as.y + adv.y; e1 = t > 0.f ? t : NEG_SLOPE * t;
            t = as.z + adv.z; e2 = t > 0.f ? t : NEG_SLOPE * t;
            t = as.w + adv.w; e3 = t > 0.f ? t : NEG_SLOPE * t;
        }
        // per-head chunk max across the wave
        float q0 = e0, q1 = e1, q2 = e2, q3 = e3;
#pragma unroll
        for (int off = 32; off; off >>= 1) {
            q0 = fmaxf(q0, __shfl_xor(q0, off));
            q1 = fmaxf(q1, __shfl_xor(q1, off));
            q2 = fmaxf(q2, __shfl_xor(q2, off));
            q3 = fmaxf(q3, __shfl_xor(q3, off));
        }
        float cm = head == 0 ? q0 : head == 1 ? q1 : head == 2 ? q2 : q3;
        float nm = fmaxf(m, cm);
        float s = __expf(m - nm);   // exp(-inf)=0 on first chunk
        a0 *= s; a1 *= s; a2 *= s; a3 *= s; dn *= s;
        m = nm;
        // hoisted exp: lane j holds x for edge base+j, all 4 heads
        float m0 = __shfl(m, 0), m1 = __shfl(m, 8), m2 = __shfl(m, 16), m3 = __shfl(m, 24);
        float x0 = __expf(e0 - m0);   // -inf -> 0 for lanes >= cnt
        float x1 = __expf(e1 - m1);
        float x2 = __expf(e2 - m2);
        float x3 = __expf(e3 - m3);

        int hs = (cnt + 1) >> 1;    // pair-steps

        // 6-deep pipeline of float4 gathers
        float4 v0, v1, v2, v3, v4, v5;
        v0 = v1 = v2 = v3 = v4 = v5 = make_float4(0.f, 0.f, 0.f, 0.f);
        {
            int sc;
            sc = half;      if (sc < cnt) { int si = __shfl(my_src, sc); v0 = *(const float4*)&Hc[(size_t)si * FDIM]; }
            sc = 2 + half;  if (sc < cnt) { int si = __shfl(my_src, sc); v1 = *(const float4*)&Hc[(size_t)si * FDIM]; }
            sc = 4 + half;  if (sc < cnt) { int si = __shfl(my_src, sc); v2 = *(const float4*)&Hc[(size_t)si * FDIM]; }
            sc = 6 + half;  if (sc < cnt) { int si = __shfl(my_src, sc); v3 = *(const float4*)&Hc[(size_t)si * FDIM]; }
            sc = 8 + half;  if (sc < cnt) { int si = __shfl(my_src, sc); v4 = *(const float4*)&Hc[(size_t)si * FDIM]; }
            sc = 10 + half; if (sc < cnt) { int si = __shfl(my_src, sc); v5 = *(const float4*)&Hc[(size_t)si * FDIM]; }
        }
        auto step = [&](int jj, float4& V) {
            if (jj < hs) {                       // wave-uniform guard
                int sc = 2 * jj + half;          // <= 63 whenever jj < hs
                float t0 = __shfl(x0, sc), t1 = __shfl(x1, sc);
                float t2 = __shfl(x2, sc), t3 = __shfl(x3, sc);
                float xh = head == 0 ? t0 : head == 1 ? t1 : head == 2 ? t2 : t3;
                a0 = fmaf(xh, V.x, a0);
                a1 = fmaf(xh, V.y, a1);
                a2 = fmaf(xh, V.z, a2);
                a3 = fmaf(xh, V.w, a3);
                dn += xh;                        // xh==0 for sc>=cnt (e=-inf)
                int sn = sc + 12;                // refill for step jj+6
                if (sn < cnt) {
                    int si = __shfl(my_src, sn);
                    V = *(const float4*)&Hc[(size_t)si * FDIM];
                }
            }
        };
        for (int j0 = 0; j0 < hs; j0 += 6) {
            step(j0 + 0, v0);
            step(j0 + 1, v1);
            step(j0 + 2, v2);
            step(j0 + 3, v3);
            step(j0 + 4, v4);
            step(j0 + 5, v5);
        }
    }

    // combine even/odd halves
    a0 += __shfl_xor(a0, 32);
    a1 += __shfl_xor(a1, 32);
    a2 += __shfl_xor(a2, 32);
    a3 += __shfl_xor(a3, 32);
    dn += __shfl_xor(dn, 32);

    if (half == 0) {
        float inv = 1.f / (dn + EPS_DEN);
        float4 bv = *(const float4*)&bias[c0];
        float o0 = fmaf(a0, inv, bv.x);
        float o1 = fmaf(a1, inv, bv.y);
        float o2 = fmaf(a2, inv, bv.z);
        float o3 = fmaf(a3, inv, bv.w);
        if (relu) {
            o0 = fmaxf(o0, 0.f); o1 = fmaxf(o1, 0.f);
            o2 = fmaxf(o2, 0.f); o3 = fmaxf(o3, 0.f);
        }
        *(float4*)&OUT[(size_t)wid * FDIM + c0] = make_float4(o0, o1, o2, o3);
    }
}

// ---------------------------------------------------------------------------

extern "C" void kernel_launch(void* const* d_in, const int* in_sizes, int n_in,
                              void* d_out, int out_size, void* d_ws, size_t ws_size,
                              hipStream_t stream) {
    const int N = in_sizes[0] / FDIM;
    const int E = in_sizes[1] / 2;

    const float* x    = (const float*)d_in[0];
    const int*   ei   = (const int*)d_in[1];
    const float* Ws   = (const float*)d_in[2];
    const float* asrc = (const float*)d_in[3];
    const float* adst = (const float*)d_in[4];
    const float* bias = (const float*)d_in[5];
    float* out = (float*)d_out;

    char* w = (char*)d_ws;
    auto carve = [&](size_t bytes) -> void* {
        void* p = (void*)w;
        w += (bytes + 255) & ~(size_t)255;
        return p;
    };
    float* hA      = (float*)carve((size_t)N * FDIM * 4);
    float* hB      = (float*)carve((size_t)N * FDIM * 4);
    float* ASb     = (float*)carve((size_t)N * HEADS * 4);
    float* ADb     = (float*)carve((size_t)N * HEADS * 4);
    int*   deg     = (int*)carve((size_t)N * 4);
    int*   row_ptr = (int*)carve((size_t)(N + 1) * 4);
    int*   cursor  = (int*)carve((size_t)N * 4);
    int*   csr_src = (int*)carve((size_t)(E + N) * 4);
    int*   part    = (int*)carve(4096);

    // ---- CSR build (dst identical across layers) ----
    hipMemsetAsync(deg, 0, (size_t)N * 4, stream);
    count_kernel<<<2048, 256, 0, stream>>>(ei + E, deg, E);
    int nblk = (N + 1023) / 1024;
    scan_sum_kernel<<<nblk, 256, 0, stream>>>(deg, part, N);
    scan_part_kernel<<<1, 64, 0, stream>>>(part, nblk, row_ptr, N);
    scan_final_kernel<<<nblk, 256, 0, stream>>>(deg, part, row_ptr, cursor, N);
    fill_kernel<<<2048, 256, 0, stream>>>(ei, cursor, csr_src, E, N);

    // ---- 3 GAT layers ----
    const float* X = x;
    for (int l = 0; l < 3; ++l) {
        gemm_alpha_kernel<<<(N + 127) / 128, 256, 0, stream>>>(
            X, Ws + (size_t)l * FDIM * FDIM, asrc + l * HEADS * CPH, adst + l * HEADS * CPH,
            hA, ASb, ADb, N);
        float* O = (l == 2) ? out : hB;
        aggregate_kernel<<<(N + 3) / 4, 256, 0, stream>>>(
            hA, ASb, ADb, row_ptr, csr_src, bias + (size_t)l * FDIM, O, N, (l < 2) ? 1 : 0);
        X = hB;
    }
}

// Round 4
// 797.570 us; speedup vs baseline: 1.1768x; 1.1768x over previous
//
#include <hip/hip_runtime.h>

#define HEADS 4
#define CPH 32
#define FDIM 128
#define NEG_SLOPE 0.2f
#define EPS_DEN 1e-16f

#define BSH 9               // 512 nodes per dst-bucket
#define BKT (1 << BSH)
#define SCHUNK 4096         // edges per bucket_scatter chunk

// ---------------------------------------------------------------------------
// CSR construction: count -> scan -> bucketed scatter -> per-bucket CSR fill
// ---------------------------------------------------------------------------

__global__ void count_kernel(const int* __restrict__ dst, int* __restrict__ deg, int E) {
    int i = blockIdx.x * blockDim.x + threadIdx.x;
    int stride = gridDim.x * blockDim.x;
    for (; i < E; i += stride) atomicAdd(&deg[dst[i]], 1);
}

__global__ void scan_sum_kernel(const int* __restrict__ deg, int* __restrict__ part, int n) {
    __shared__ int sd[256];
    int t = threadIdx.x;
    int base = blockIdx.x * 1024 + t * 4;
    int s = 0;
#pragma unroll
    for (int j = 0; j < 4; ++j) { int i = base + j; if (i < n) s += deg[i] + 1; } // +1 self loop
    sd[t] = s;
    __syncthreads();
    for (int d = 128; d; d >>= 1) { if (t < d) sd[t] += sd[t + d]; __syncthreads(); }
    if (t == 0) part[blockIdx.x] = sd[0];
}

__global__ void scan_part_kernel(int* part, int nblk, int* row_ptr, int n) {
    if (blockIdx.x == 0 && threadIdx.x == 0) {
        int run = 0;
        for (int i = 0; i < nblk; ++i) { int v = part[i]; part[i] = run; run += v; }
        row_ptr[n] = run;   // == E + N
    }
}

__global__ void scan_final_kernel(const int* __restrict__ deg, const int* __restrict__ part,
                                  int* __restrict__ row_ptr, int n) {
    __shared__ int sd[256];
    int t = threadIdx.x;
    int base = blockIdx.x * 1024 + t * 4;
    int v[4]; int s = 0;
#pragma unroll
    for (int j = 0; j < 4; ++j) { int i = base + j; v[j] = (i < n) ? deg[i] + 1 : 0; s += v[j]; }
    sd[t] = s;
    __syncthreads();
    for (int d = 1; d < 256; d <<= 1) {
        int x = sd[t];
        int y = (t >= d) ? sd[t - d] : 0;
        __syncthreads();
        sd[t] = x + y;
        __syncthreads();
    }
    int off = part[blockIdx.x] + sd[t] - s;
#pragma unroll
    for (int j = 0; j < 4; ++j) {
        int i = base + j;
        if (i < n) { row_ptr[i] = off; off += v[j]; }
    }
}

__global__ void init_bcur_kernel(const int* __restrict__ row_ptr, int* __restrict__ bcur,
                                 int N, int NB) {
    int b = blockIdx.x * blockDim.x + threadIdx.x;
    if (b < NB) bcur[b] = row_ptr[min(b << BSH, N)];
}

// Scatter (src,dst) pairs into dst-bucket-grouped order. Per chunk: LDS
// histogram -> one global atomicAdd per touched bucket -> LDS-cursor scatter.
// Consecutive same-bucket edges of a block land contiguously (low write amp).
__global__ __launch_bounds__(256) void bucket_scatter_kernel(
        const int* __restrict__ ei, int* __restrict__ bcur, int2* __restrict__ pairs,
        int E, int N, int NB) {
    __shared__ int hist[512];
    __shared__ int lcur[512];
    int ET = E + N;
    int tid = threadIdx.x;
    for (int cbase = blockIdx.x * SCHUNK; cbase < ET; cbase += gridDim.x * SCHUNK) {
        int cend = min(cbase + SCHUNK, ET);
        for (int b = tid; b < NB; b += 256) hist[b] = 0;
        __syncthreads();
        for (int i = cbase + tid; i < cend; i += 256) {
            int d = (i < E) ? ei[E + i] : (i - E);
            atomicAdd(&hist[d >> BSH], 1);
        }
        __syncthreads();
        for (int b = tid; b < NB; b += 256) {
            int c = hist[b];
            lcur[b] = c ? atomicAdd(&bcur[b], c) : 0;
        }
        __syncthreads();
        for (int i = cbase + tid; i < cend; i += 256) {
            int s, d;
            if (i < E) { s = ei[i]; d = ei[E + i]; }
            else       { s = i - E; d = s; }
            int p = atomicAdd(&lcur[d >> BSH], 1);
            pairs[p] = make_int2(s, d);
        }
        __syncthreads();
    }
}

// One block per bucket: cursors for the bucket's nodes live in LDS; all
// csr_src writes fall in the bucket's ~35KB window -> L2-resident, amp ~1.
__global__ __launch_bounds__(256) void csr_from_buckets_kernel(
        const int2* __restrict__ pairs, const int* __restrict__ row_ptr,
        int* __restrict__ csr_src, int N) {
    __shared__ int lcur[BKT];
    int lo = blockIdx.x << BSH;
    int hi = min(lo + BKT, N);
    int tid = threadIdx.x;
    for (int i = lo + tid; i < hi; i += 256) lcur[i - lo] = row_ptr[i];
    __syncthreads();
    int s0 = row_ptr[lo];
    int s1 = row_ptr[hi];
    for (int j = s0 + tid; j < s1; j += 256) {
        int2 pr = pairs[j];
        int p = atomicAdd(&lcur[pr.y - lo], 1);
        csr_src[p] = pr.x;
    }
}

// ---------------------------------------------------------------------------
// Fused GEMM (h = X @ W) + alpha_src/alpha_dst per node  [R2-measured version]
// Tile: 64 rows x 128 cols, K-chunks of 32. Thread = 4 rows x (4+4) cols.
// ---------------------------------------------------------------------------
#define AS_LD 68

__global__ __launch_bounds__(256) void gemm_alpha_kernel(
        const float* __restrict__ X, const float* __restrict__ W,
        const float* __restrict__ a_src, const float* __restrict__ a_dst,
        float* __restrict__ H, float* __restrict__ ASo, float* __restrict__ ADo, int n) {
    __shared__ float As[32][AS_LD];  // transposed A chunk: As[k][row]
    __shared__ float Bs[32][128];
    int tid = threadIdx.x;
    int block_row = blockIdx.x * 64;
    int cg = tid & 15;
    int rg = tid >> 4;
    int r0 = rg * 4;
    int ca = cg * 4;
    int cb = 64 + cg * 4;
    float acc[4][8];
#pragma unroll
    for (int i = 0; i < 4; ++i)
#pragma unroll
        for (int j = 0; j < 8; ++j) acc[i][j] = 0.f;

    for (int k0 = 0; k0 < 128; k0 += 32) {
        for (int t = tid; t < 512; t += 256) {
            int row = t >> 3;
            int kk = (t & 7) << 2;
            int grow = block_row + row;
            float4 v = make_float4(0.f, 0.f, 0.f, 0.f);
            if (grow < n) v = *(const float4*)&X[(size_t)grow * FDIM + k0 + kk];
            As[kk + 0][row] = v.x; As[kk + 1][row] = v.y;
            As[kk + 2][row] = v.z; As[kk + 3][row] = v.w;
        }
        for (int t = tid; t < 1024; t += 256) {
            int kr = t >> 5;
            int c4 = (t & 31) << 2;
            *(float4*)&Bs[kr][c4] = *(const float4*)&W[(size_t)(k0 + kr) * FDIM + c4];
        }
        __syncthreads();
#pragma unroll
        for (int k = 0; k < 32; ++k) {
            float4 a  = *(const float4*)&As[k][r0];
            float4 b1 = *(const float4*)&Bs[k][ca];
            float4 b2 = *(const float4*)&Bs[k][cb];
            float av[4] = {a.x, a.y, a.z, a.w};
            float bv[8] = {b1.x, b1.y, b1.z, b1.w, b2.x, b2.y, b2.z, b2.w};
#pragma unroll
            for (int i = 0; i < 4; ++i)
#pragma unroll
                for (int j = 0; j < 8; ++j) acc[i][j] = fmaf(av[i], bv[j], acc[i][j]);
        }
        __syncthreads();
    }

    int hd_a = cg >> 3;
    int hd_b = 2 + hd_a;
    int co = (cg & 7) * 4;
    float4 wsa = *(const float4*)&a_src[hd_a * CPH + co];
    float4 wsb = *(const float4*)&a_src[hd_b * CPH + co];
    float4 wda = *(const float4*)&a_dst[hd_a * CPH + co];
    float4 wdb = *(const float4*)&a_dst[hd_b * CPH + co];
#pragma unroll
    for (int i = 0; i < 4; ++i) {
        int grow = block_row + r0 + i;
        bool ok = grow < n;
        if (ok) {
            *(float4*)&H[(size_t)grow * FDIM + ca] =
                make_float4(acc[i][0], acc[i][1], acc[i][2], acc[i][3]);
            *(float4*)&H[(size_t)grow * FDIM + cb] =
                make_float4(acc[i][4], acc[i][5], acc[i][6], acc[i][7]);
        }
        float psa = acc[i][0] * wsa.x + acc[i][1] * wsa.y + acc[i][2] * wsa.z + acc[i][3] * wsa.w;
        float psb = acc[i][4] * wsb.x + acc[i][5] * wsb.y + acc[i][6] * wsb.z + acc[i][7] * wsb.w;
        float pda = acc[i][0] * wda.x + acc[i][1] * wda.y + acc[i][2] * wda.z + acc[i][3] * wda.w;
        float pdb = acc[i][4] * wdb.x + acc[i][5] * wdb.y + acc[i][6] * wdb.z + acc[i][7] * wdb.w;
#pragma unroll
        for (int off = 1; off <= 4; off <<= 1) {
            psa += __shfl_xor(psa, off);
            psb += __shfl_xor(psb, off);
            pda += __shfl_xor(pda, off);
            pdb += __shfl_xor(pdb, off);
        }
        if (ok && (cg & 7) == 0) {
            ASo[(size_t)grow * HEADS + hd_a] = psa;
            ASo[(size_t)grow * HEADS + hd_b] = psb;
            ADo[(size_t)grow * HEADS + hd_a] = pda;
            ADo[(size_t)grow * HEADS + hd_b] = pdb;
        }
    }
}

// ---------------------------------------------------------------------------
// Aggregation [R2-measured version: 138us, VGPR=32, occ 77%]
// One wave per dst node; lanes 0-31 even edges, 32-63 odd edges; lane owns
// 4 channels c0=4*(lane&31). Hoisted exp; 2-deep float4 gather pipeline.
// ---------------------------------------------------------------------------
__global__ __launch_bounds__(256) void aggregate_kernel(
        const float* __restrict__ H, const float* __restrict__ ASi, const float* __restrict__ ADi,
        const int* __restrict__ row_ptr, const int* __restrict__ csr_src,
        const float* __restrict__ bias, float* __restrict__ OUT, int n, int relu) {
    int wid = (int)((blockIdx.x * (size_t)blockDim.x + threadIdx.x) >> 6);
    if (wid >= n) return;
    int lane = threadIdx.x & 63;
    int half = lane >> 5;
    int lq   = lane & 31;
    int head = lq >> 3;
    int c0   = lq << 2;

    int start = row_ptr[wid];
    int end   = row_ptr[wid + 1];
    float4 adv = *(const float4*)&ADi[(size_t)wid * HEADS];

    float m = -INFINITY;
    float dn = 0.f;
    float a0 = 0.f, a1 = 0.f, a2 = 0.f, a3 = 0.f;

    for (int base = start; base < end; base += 64) {
        int cnt = min(64, end - base);
        int idx = base + lane;
        float e0 = -INFINITY, e1 = -INFINITY, e2 = -INFINITY, e3 = -INFINITY;
        int my_src = 0;
        if (idx < end) {
            my_src = csr_src[idx];
            float4 as = *(const float4*)&ASi[(size_t)my_src * HEADS];
            float t;
            t = as.x + adv.x; e0 = t > 0.f ? t : NEG_SLOPE * t;
            t = as.y + adv.y; e1 = t > 0.f ? t : NEG_SLOPE * t;
            t = as.z + adv.z; e2 = t > 0.f ? t : NEG_SLOPE * t;
            t = as.w + adv.w; e3 = t > 0.f ? t : NEG_SLOPE * t;
        }
        float q0 = e0, q1 = e1, q2 = e2, q3 = e3;
#pragma unroll
        for (int off = 32; off; off >>= 1) {
            q0 = fmaxf(q0, __shfl_xor(q0, off));
            q1 = fmaxf(q1, __shfl_xor(q1, off));
            q2 = fmaxf(q2, __shfl_xor(q2, off));
            q3 = fmaxf(q3, __shfl_xor(q3, off));
        }
        float cm = head == 0 ? q0 : head == 1 ? q1 : head == 2 ? q2 : q3;
        float nm = fmaxf(m, cm);
        float s = __expf(m - nm);
        a0 *= s; a1 *= s; a2 *= s; a3 *= s; dn *= s;
        m = nm;
        float m0 = __shfl(m, 0), m1 = __shfl(m, 8), m2 = __shfl(m, 16), m3 = __shfl(m, 24);
        float x0 = __expf(e0 - m0);
        float x1 = __expf(e1 - m1);
        float x2 = __expf(e2 - m2);
        float x3 = __expf(e3 - m3);

        int hs = (cnt + 1) >> 1;
        float4 va = make_float4(0.f, 0.f, 0.f, 0.f);
        float4 vb = make_float4(0.f, 0.f, 0.f, 0.f);
        int sA = half;
        if (sA < cnt) {
            int sidx = __shfl(my_src, sA);
            va = *(const float4*)&H[(size_t)sidx * FDIM + c0];
        }
        int sB = half + 2;
        if (sB < cnt) {
            int sidx = __shfl(my_src, sB);
            vb = *(const float4*)&H[(size_t)sidx * FDIM + c0];
        }
        for (int j = 0; j < hs; ++j) {
            int sc = 2 * j + half;
            float t0 = __shfl(x0, sc), t1 = __shfl(x1, sc);
            float t2 = __shfl(x2, sc), t3 = __shfl(x3, sc);
            float xh = head == 0 ? t0 : head == 1 ? t1 : head == 2 ? t2 : t3;
            float4 cv = va;
            va = vb;
            int sn = sc + 4;
            if (sn < cnt) {
                int sidx = __shfl(my_src, sn);
                vb = *(const float4*)&H[(size_t)sidx * FDIM + c0];
            }
            a0 = fmaf(xh, cv.x, a0);
            a1 = fmaf(xh, cv.y, a1);
            a2 = fmaf(xh, cv.z, a2);
            a3 = fmaf(xh, cv.w, a3);
            dn += xh;
        }
    }

    a0 += __shfl_xor(a0, 32);
    a1 += __shfl_xor(a1, 32);
    a2 += __shfl_xor(a2, 32);
    a3 += __shfl_xor(a3, 32);
    dn += __shfl_xor(dn, 32);

    if (half == 0) {
        float inv = 1.f / (dn + EPS_DEN);
        float4 bv = *(const float4*)&bias[c0];
        float o0 = fmaf(a0, inv, bv.x);
        float o1 = fmaf(a1, inv, bv.y);
        float o2 = fmaf(a2, inv, bv.z);
        float o3 = fmaf(a3, inv, bv.w);
        if (relu) {
            o0 = fmaxf(o0, 0.f); o1 = fmaxf(o1, 0.f);
            o2 = fmaxf(o2, 0.f); o3 = fmaxf(o3, 0.f);
        }
        *(float4*)&OUT[(size_t)wid * FDIM + c0] = make_float4(o0, o1, o2, o3);
    }
}

// ---------------------------------------------------------------------------

extern "C" void kernel_launch(void* const* d_in, const int* in_sizes, int n_in,
                              void* d_out, int out_size, void* d_ws, size_t ws_size,
                              hipStream_t stream) {
    const int N = in_sizes[0] / FDIM;
    const int E = in_sizes[1] / 2;
    const int NB = (N + BKT - 1) >> BSH;

    const float* x    = (const float*)d_in[0];
    const int*   ei   = (const int*)d_in[1];
    const float* Ws   = (const float*)d_in[2];
    const float* asrc = (const float*)d_in[3];
    const float* adst = (const float*)d_in[4];
    const float* bias = (const float*)d_in[5];
    float* out = (float*)d_out;

    char* w = (char*)d_ws;
    auto carve = [&](size_t bytes) -> void* {
        void* p = (void*)w;
        w += (bytes + 255) & ~(size_t)255;
        return p;
    };
    float* hA      = (float*)carve((size_t)N * FDIM * 4);
    float* hB      = (float*)carve((size_t)N * FDIM * 4);
    float* ASb     = (float*)carve((size_t)N * HEADS * 4);
    float* ADb     = (float*)carve((size_t)N * HEADS * 4);
    int*   deg     = (int*)carve((size_t)N * 4);
    int*   row_ptr = (int*)carve((size_t)(N + 1) * 4);
    int*   csr_src = (int*)carve((size_t)(E + N) * 4);
    int*   part    = (int*)carve(4096);
    int*   bcur    = (int*)carve(4096);
    int2*  pairs   = (int2*)hB;   // alias: hB is dead until aggregate layer 0

    // ---- CSR build (dst identical across layers) ----
    hipMemsetAsync(deg, 0, (size_t)N * 4, stream);
    count_kernel<<<2048, 256, 0, stream>>>(ei + E, deg, E);
    int nblk = (N + 1023) / 1024;
    scan_sum_kernel<<<nblk, 256, 0, stream>>>(deg, part, N);
    scan_part_kernel<<<1, 64, 0, stream>>>(part, nblk, row_ptr, N);
    scan_final_kernel<<<nblk, 256, 0, stream>>>(deg, part, row_ptr, N);
    init_bcur_kernel<<<(NB + 255) / 256, 256, 0, stream>>>(row_ptr, bcur, N, NB);
    int sblk = min(416, (E + N + SCHUNK - 1) / SCHUNK);
    bucket_scatter_kernel<<<sblk, 256, 0, stream>>>(ei, bcur, pairs, E, N, NB);
    csr_from_buckets_kernel<<<NB, 256, 0, stream>>>(pairs, row_ptr, csr_src, N);

    // ---- 3 GAT layers ----
    const float* X = x;
    for (int l = 0; l < 3; ++l) {
        gemm_alpha_kernel<<<(N + 63) / 64, 256, 0, stream>>>(
            X, Ws + (size_t)l * FDIM * FDIM, asrc + l * HEADS * CPH, adst + l * HEADS * CPH,
            hA, ASb, ADb, N);
        float* O = (l == 2) ? out : hB;
        aggregate_kernel<<<(N + 3) / 4, 256, 0, stream>>>(
            hA, ASb, ADb, row_ptr, csr_src, bias + (size_t)l * FDIM, O, N, (l < 2) ? 1 : 0);
        X = hB;
    }
}

// Round 6
// 749.562 us; speedup vs baseline: 1.2522x; 1.0640x over previous
//
#include <hip/hip_runtime.h>

#define HEADS 4
#define CPH 32
#define FDIM 128
#define NEG_SLOPE 0.2f
#define EPS_DEN 1e-16f

#define BSH 9               // 512 nodes per dst-bucket
#define BKT (1 << BSH)
#define SCHUNK 4096         // edges per bucket_scatter chunk

// ---------------------------------------------------------------------------
// CSR construction v2: bucket-count -> tiny scan -> bucketed scatter ->
// per-bucket {degree hist + LDS scan -> row_ptr + csr fill}.
// No per-node global atomics, no N-length scan kernels.
// ---------------------------------------------------------------------------

__global__ __launch_bounds__(256) void bucket_count_kernel(
        const int* __restrict__ ei, int* __restrict__ bcnt, int E, int N, int NB) {
    __shared__ int hist[512];
    int tid = threadIdx.x;
    int ET = E + N;
    for (int b = tid; b < 512; b += 256) hist[b] = 0;
    __syncthreads();
    int i = blockIdx.x * blockDim.x + tid;
    int stride = gridDim.x * blockDim.x;
    for (; i < ET; i += stride) {
        int d = (i < E) ? ei[E + i] : (i - E);
        atomicAdd(&hist[d >> BSH], 1);
    }
    __syncthreads();
    for (int b = tid; b < NB; b += 256) {
        int c = hist[b];
        if (c) atomicAdd(&bcnt[b], c);
    }
}

__global__ void bucket_scan_kernel(const int* __restrict__ bcnt, int* __restrict__ bbase,
                                   int* __restrict__ bcur, int NB,
                                   int* __restrict__ row_ptr, int N) {
    if (blockIdx.x == 0 && threadIdx.x == 0) {
        int run = 0;
        for (int b = 0; b < NB; ++b) { bbase[b] = run; bcur[b] = run; run += bcnt[b]; }
        bbase[NB] = run;        // == E + N
        row_ptr[N] = run;
    }
}

__global__ __launch_bounds__(256) void bucket_scatter_kernel(
        const int* __restrict__ ei, int* __restrict__ bcur, int2* __restrict__ pairs,
        int E, int N, int NB) {
    __shared__ int hist[512];
    __shared__ int lcur[512];
    int ET = E + N;
    int tid = threadIdx.x;
    for (int cbase = blockIdx.x * SCHUNK; cbase < ET; cbase += gridDim.x * SCHUNK) {
        int cend = min(cbase + SCHUNK, ET);
        for (int b = tid; b < NB; b += 256) hist[b] = 0;
        __syncthreads();
        for (int i = cbase + tid; i < cend; i += 256) {
            int d = (i < E) ? ei[E + i] : (i - E);
            atomicAdd(&hist[d >> BSH], 1);
        }
        __syncthreads();
        for (int b = tid; b < NB; b += 256) {
            int c = hist[b];
            lcur[b] = c ? atomicAdd(&bcur[b], c) : 0;
        }
        __syncthreads();
        for (int i = cbase + tid; i < cend; i += 256) {
            int s, d;
            if (i < E) { s = ei[i]; d = ei[E + i]; }
            else       { s = i - E; d = s; }
            int p = atomicAdd(&lcur[d >> BSH], 1);
            pairs[p] = make_int2(s, d);
        }
        __syncthreads();
    }
}

// One block per bucket: LDS degree histogram -> in-LDS exclusive scan ->
// row_ptr write + cursor scatter. csr_src writes stay in the bucket's
// ~35KB window -> L2-resident.
__global__ __launch_bounds__(256) void csr_from_buckets_kernel(
        const int2* __restrict__ pairs, const int* __restrict__ bbase,
        int* __restrict__ row_ptr, int* __restrict__ csr_src, int N) {
    __shared__ int hist[BKT];
    __shared__ int ssum[256];
    int b  = blockIdx.x;
    int lo = b << BSH;
    int hi = min(lo + BKT, N);
    int nn = hi - lo;
    int tid = threadIdx.x;
    for (int i = tid; i < BKT; i += 256) hist[i] = 0;
    __syncthreads();
    int s0 = bbase[b];
    int s1 = bbase[b + 1];
    for (int j = s0 + tid; j < s1; j += 256)
        atomicAdd(&hist[pairs[j].y - lo], 1);
    __syncthreads();
    // exclusive scan over BKT=512 entries; thread owns elements 2t, 2t+1
    int e0 = hist[2 * tid];
    int e1 = hist[2 * tid + 1];
    int ps = e0 + e1;
    ssum[tid] = ps;
    __syncthreads();
    for (int d = 1; d < 256; d <<= 1) {
        int v = ssum[tid];
        int u = (tid >= d) ? ssum[tid - d] : 0;
        __syncthreads();
        ssum[tid] = v + u;
        __syncthreads();
    }
    int excl = ssum[tid] - ps;          // exclusive prefix of this pair
    int p0 = s0 + excl;
    int p1 = p0 + e0;
    if (2 * tid < nn)     row_ptr[lo + 2 * tid]     = p0;
    if (2 * tid + 1 < nn) row_ptr[lo + 2 * tid + 1] = p1;
    hist[2 * tid]     = p0;             // reuse hist as cursors
    hist[2 * tid + 1] = p1;
    __syncthreads();
    for (int j = s0 + tid; j < s1; j += 256) {
        int2 pr = pairs[j];
        int p = atomicAdd(&hist[pr.y - lo], 1);
        csr_src[p] = pr.x;
    }
}

// ---------------------------------------------------------------------------
// Fused GEMM (h = X @ W) + alpha_src/alpha_dst per node  [R2/R4-measured]
// Tile: 64 rows x 128 cols, K-chunks of 32. Thread = 4 rows x (4+4) cols.
// ---------------------------------------------------------------------------
#define AS_LD 68

__global__ __launch_bounds__(256) void gemm_alpha_kernel(
        const float* __restrict__ X, const float* __restrict__ W,
        const float* __restrict__ a_src, const float* __restrict__ a_dst,
        float* __restrict__ H, float* __restrict__ ASo, float* __restrict__ ADo, int n) {
    __shared__ float As[32][AS_LD];  // transposed A chunk: As[k][row]
    __shared__ float Bs[32][128];
    int tid = threadIdx.x;
    int block_row = blockIdx.x * 64;
    int cg = tid & 15;
    int rg = tid >> 4;
    int r0 = rg * 4;
    int ca = cg * 4;
    int cb = 64 + cg * 4;
    float acc[4][8];
#pragma unroll
    for (int i = 0; i < 4; ++i)
#pragma unroll
        for (int j = 0; j < 8; ++j) acc[i][j] = 0.f;

    for (int k0 = 0; k0 < 128; k0 += 32) {
        for (int t = tid; t < 512; t += 256) {
            int row = t >> 3;
            int kk = (t & 7) << 2;
            int grow = block_row + row;
            float4 v = make_float4(0.f, 0.f, 0.f, 0.f);
            if (grow < n) v = *(const float4*)&X[(size_t)grow * FDIM + k0 + kk];
            As[kk + 0][row] = v.x; As[kk + 1][row] = v.y;
            As[kk + 2][row] = v.z; As[kk + 3][row] = v.w;
        }
        for (int t = tid; t < 1024; t += 256) {
            int kr = t >> 5;
            int c4 = (t & 31) << 2;
            *(float4*)&Bs[kr][c4] = *(const float4*)&W[(size_t)(k0 + kr) * FDIM + c4];
        }
        __syncthreads();
#pragma unroll
        for (int k = 0; k < 32; ++k) {
            float4 a  = *(const float4*)&As[k][r0];
            float4 b1 = *(const float4*)&Bs[k][ca];
            float4 b2 = *(const float4*)&Bs[k][cb];
            float av[4] = {a.x, a.y, a.z, a.w};
            float bv[8] = {b1.x, b1.y, b1.z, b1.w, b2.x, b2.y, b2.z, b2.w};
#pragma unroll
            for (int i = 0; i < 4; ++i)
#pragma unroll
                for (int j = 0; j < 8; ++j) acc[i][j] = fmaf(av[i], bv[j], acc[i][j]);
        }
        __syncthreads();
    }

    int hd_a = cg >> 3;
    int hd_b = 2 + hd_a;
    int co = (cg & 7) * 4;
    float4 wsa = *(const float4*)&a_src[hd_a * CPH + co];
    float4 wsb = *(const float4*)&a_src[hd_b * CPH + co];
    float4 wda = *(const float4*)&a_dst[hd_a * CPH + co];
    float4 wdb = *(const float4*)&a_dst[hd_b * CPH + co];
#pragma unroll
    for (int i = 0; i < 4; ++i) {
        int grow = block_row + r0 + i;
        bool ok = grow < n;
        if (ok) {
            *(float4*)&H[(size_t)grow * FDIM + ca] =
                make_float4(acc[i][0], acc[i][1], acc[i][2], acc[i][3]);
            *(float4*)&H[(size_t)grow * FDIM + cb] =
                make_float4(acc[i][4], acc[i][5], acc[i][6], acc[i][7]);
        }
        float psa = acc[i][0] * wsa.x + acc[i][1] * wsa.y + acc[i][2] * wsa.z + acc[i][3] * wsa.w;
        float psb = acc[i][4] * wsb.x + acc[i][5] * wsb.y + acc[i][6] * wsb.z + acc[i][7] * wsb.w;
        float pda = acc[i][0] * wda.x + acc[i][1] * wda.y + acc[i][2] * wda.z + acc[i][3] * wda.w;
        float pdb = acc[i][4] * wdb.x + acc[i][5] * wdb.y + acc[i][6] * wdb.z + acc[i][7] * wdb.w;
#pragma unroll
        for (int off = 1; off <= 4; off <<= 1) {
            psa += __shfl_xor(psa, off);
            psb += __shfl_xor(psb, off);
            pda += __shfl_xor(pda, off);
            pdb += __shfl_xor(pdb, off);
        }
        if (ok && (cg & 7) == 0) {
            ASo[(size_t)grow * HEADS + hd_a] = psa;
            ASo[(size_t)grow * HEADS + hd_b] = psb;
            ADo[(size_t)grow * HEADS + hd_a] = pda;
            ADo[(size_t)grow * HEADS + hd_b] = pdb;
        }
    }
}

// ---------------------------------------------------------------------------
// Aggregation [R2/R4-measured: 137us, VGPR=32, occ 77%; fp32 H — fp16 is
// permanently dead: bf16-quantized ref leaves only ~3e-4 error budget]
// ---------------------------------------------------------------------------
__global__ __launch_bounds__(256) void aggregate_kernel(
        const float* __restrict__ H, const float* __restrict__ ASi, const float* __restrict__ ADi,
        const int* __restrict__ row_ptr, const int* __restrict__ csr_src,
        const float* __restrict__ bias, float* __restrict__ OUT, int n, int relu) {
    int wid = (int)((blockIdx.x * (size_t)blockDim.x + threadIdx.x) >> 6);
    if (wid >= n) return;
    int lane = threadIdx.x & 63;
    int half = lane >> 5;
    int lq   = lane & 31;
    int head = lq >> 3;
    int c0   = lq << 2;

    int start = row_ptr[wid];
    int end   = row_ptr[wid + 1];
    float4 adv = *(const float4*)&ADi[(size_t)wid * HEADS];

    float m = -INFINITY;
    float dn = 0.f;
    float a0 = 0.f, a1 = 0.f, a2 = 0.f, a3 = 0.f;

    for (int base = start; base < end; base += 64) {
        int cnt = min(64, end - base);
        int idx = base + lane;
        float e0 = -INFINITY, e1 = -INFINITY, e2 = -INFINITY, e3 = -INFINITY;
        int my_src = 0;
        if (idx < end) {
            my_src = csr_src[idx];
            float4 as = *(const float4*)&ASi[(size_t)my_src * HEADS];
            float t;
            t = as.x + adv.x; e0 = t > 0.f ? t : NEG_SLOPE * t;
            t = as.y + adv.y; e1 = t > 0.f ? t : NEG_SLOPE * t;
            t = as.z + adv.z; e2 = t > 0.f ? t : NEG_SLOPE * t;
            t = as.w + adv.w; e3 = t > 0.f ? t : NEG_SLOPE * t;
        }
        float q0 = e0, q1 = e1, q2 = e2, q3 = e3;
#pragma unroll
        for (int off = 32; off; off >>= 1) {
            q0 = fmaxf(q0, __shfl_xor(q0, off));
            q1 = fmaxf(q1, __shfl_xor(q1, off));
            q2 = fmaxf(q2, __shfl_xor(q2, off));
            q3 = fmaxf(q3, __shfl_xor(q3, off));
        }
        float cm = head == 0 ? q0 : head == 1 ? q1 : head == 2 ? q2 : q3;
        float nm = fmaxf(m, cm);
        float s = __expf(m - nm);
        a0 *= s; a1 *= s; a2 *= s; a3 *= s; dn *= s;
        m = nm;
        float m0 = __shfl(m, 0), m1 = __shfl(m, 8), m2 = __shfl(m, 16), m3 = __shfl(m, 24);
        float x0 = __expf(e0 - m0);
        float x1 = __expf(e1 - m1);
        float x2 = __expf(e2 - m2);
        float x3 = __expf(e3 - m3);

        int hs = (cnt + 1) >> 1;
        float4 va = make_float4(0.f, 0.f, 0.f, 0.f);
        float4 vb = make_float4(0.f, 0.f, 0.f, 0.f);
        int sA = half;
        if (sA < cnt) {
            int sidx = __shfl(my_src, sA);
            va = *(const float4*)&H[(size_t)sidx * FDIM + c0];
        }
        int sB = half + 2;
        if (sB < cnt) {
            int sidx = __shfl(my_src, sB);
            vb = *(const float4*)&H[(size_t)sidx * FDIM + c0];
        }
        for (int j = 0; j < hs; ++j) {
            int sc = 2 * j + half;
            float t0 = __shfl(x0, sc), t1 = __shfl(x1, sc);
            float t2 = __shfl(x2, sc), t3 = __shfl(x3, sc);
            float xh = head == 0 ? t0 : head == 1 ? t1 : head == 2 ? t2 : t3;
            float4 cv = va;
            va = vb;
            int sn = sc + 4;
            if (sn < cnt) {
                int sidx = __shfl(my_src, sn);
                vb = *(const float4*)&H[(size_t)sidx * FDIM + c0];
            }
            a0 = fmaf(xh, cv.x, a0);
            a1 = fmaf(xh, cv.y, a1);
            a2 = fmaf(xh, cv.z, a2);
            a3 = fmaf(xh, cv.w, a3);
            dn += xh;
        }
    }

    a0 += __shfl_xor(a0, 32);
    a1 += __shfl_xor(a1, 32);
    a2 += __shfl_xor(a2, 32);
    a3 += __shfl_xor(a3, 32);
    dn += __shfl_xor(dn, 32);

    if (half == 0) {
        float inv = 1.f / (dn + EPS_DEN);
        float4 bv = *(const float4*)&bias[c0];
        float o0 = fmaf(a0, inv, bv.x);
        float o1 = fmaf(a1, inv, bv.y);
        float o2 = fmaf(a2, inv, bv.z);
        float o3 = fmaf(a3, inv, bv.w);
        if (relu) {
            o0 = fmaxf(o0, 0.f); o1 = fmaxf(o1, 0.f);
            o2 = fmaxf(o2, 0.f); o3 = fmaxf(o3, 0.f);
        }
        *(float4*)&OUT[(size_t)wid * FDIM + c0] = make_float4(o0, o1, o2, o3);
    }
}

// ---------------------------------------------------------------------------

extern "C" void kernel_launch(void* const* d_in, const int* in_sizes, int n_in,
                              void* d_out, int out_size, void* d_ws, size_t ws_size,
                              hipStream_t stream) {
    const int N = in_sizes[0] / FDIM;
    const int E = in_sizes[1] / 2;
    const int NB = (N + BKT - 1) >> BSH;

    const float* x    = (const float*)d_in[0];
    const int*   ei   = (const int*)d_in[1];
    const float* Ws   = (const float*)d_in[2];
    const float* asrc = (const float*)d_in[3];
    const float* adst = (const float*)d_in[4];
    const float* bias = (const float*)d_in[5];
    float* out = (float*)d_out;

    char* w = (char*)d_ws;
    auto carve = [&](size_t bytes) -> void* {
        void* p = (void*)w;
        w += (bytes + 255) & ~(size_t)255;
        return p;
    };
    float* hA      = (float*)carve((size_t)N * FDIM * 4);
    float* hB      = (float*)carve((size_t)N * FDIM * 4);
    float* ASb     = (float*)carve((size_t)N * HEADS * 4);
    float* ADb     = (float*)carve((size_t)N * HEADS * 4);
    int*   row_ptr = (int*)carve((size_t)(N + 1) * 4);
    int*   csr_src = (int*)carve((size_t)(E + N) * 4);
    int*   bcnt    = (int*)carve(4096);
    int*   bbase   = (int*)carve(4096);
    int*   bcur    = (int*)carve(4096);
    int2*  pairs   = (int2*)hB;   // alias: hB is dead until aggregate layer 0

    // ---- CSR build v2 (dst identical across layers) ----
    hipMemsetAsync(bcnt, 0, (size_t)NB * 4, stream);
    bucket_count_kernel<<<1024, 256, 0, stream>>>(ei, bcnt, E, N, NB);
    bucket_scan_kernel<<<1, 64, 0, stream>>>(bcnt, bbase, bcur, NB, row_ptr, N);
    int sblk = min(416, (E + N + SCHUNK - 1) / SCHUNK);
    bucket_scatter_kernel<<<sblk, 256, 0, stream>>>(ei, bcur, pairs, E, N, NB);
    csr_from_buckets_kernel<<<NB, 256, 0, stream>>>(pairs, bbase, row_ptr, csr_src, N);

    // ---- 3 GAT layers ----
    const float* X = x;
    for (int l = 0; l < 3; ++l) {
        gemm_alpha_kernel<<<(N + 63) / 64, 256, 0, stream>>>(
            X, Ws + (size_t)l * FDIM * FDIM, asrc + l * HEADS * CPH, adst + l * HEADS * CPH,
            hA, ASb, ADb, N);
        float* O = (l == 2) ? out : hB;
        aggregate_kernel<<<(N + 3) / 4, 256, 0, stream>>>(
            hA, ASb, ADb, row_ptr, csr_src, bias + (size_t)l * FDIM, O, N, (l < 2) ? 1 : 0);
        X = hB;
    }
}